// Round 14
// baseline (188.669 us; speedup 1.0000x reference)
//
#include <hip/hip_runtime.h>

#define ED 512
#define NH 8
#define HD 64
#define BB 4
#define SEQ 2048
#define MTOT (BB*SEQ)   // 8192

typedef float f32x4 __attribute__((ext_vector_type(4)));
typedef float f32x16 __attribute__((ext_vector_type(16)));
typedef __bf16 bf16x8 __attribute__((ext_vector_type(8)));
typedef int i32x2 __attribute__((ext_vector_type(2)));
typedef unsigned int u32x4 __attribute__((ext_vector_type(4)));

__device__ __forceinline__ unsigned short f2bf(float f) {
  unsigned int u = __float_as_uint(f);
  u += 0x7FFFu + ((u >> 16) & 1u);
  return (unsigned short)(u >> 16);
}

__device__ __forceinline__ unsigned int cvtpk(float lo, float hi) {
  unsigned int r;
  asm volatile("v_cvt_pk_bf16_f32 %0, %1, %2" : "=v"(r) : "v"(lo), "v"(hi));
  return r;
}

__device__ __forceinline__ void async16(const void* g, void* l) {
  auto gp = (const __attribute__((address_space(1))) unsigned int*)(uintptr_t)(g);
  auto lp = (__attribute__((address_space(3))) unsigned int*)(uintptr_t)(l);
  __builtin_amdgcn_global_load_lds(gp, lp, 16, 0, 0);
}

// ---------------- fused fp32 -> bf16 convert (x, qkv_w, proj_w in one launch) ----
#define N4_X   1048576   // (4*2048*512)/4
#define N4_WQ  196608    // (3*512*512)/4
#define N4_WP  65536     // (512*512)/4
__global__ void cvt_all(const float* __restrict__ x,
                        const float* __restrict__ wq_in,
                        const float* __restrict__ wp_in,
                        unsigned short* __restrict__ xb,
                        unsigned short* __restrict__ wq,
                        unsigned short* __restrict__ wp) {
  int i = blockIdx.x * blockDim.x + threadIdx.x;
  const float* src; unsigned short* dst; int off;
  if (i < N4_X)              { src = x;     dst = xb; off = i; }
  else if (i < N4_X + N4_WQ) { src = wq_in; dst = wq; off = i - N4_X; }
  else                       { src = wp_in; dst = wp; off = i - (N4_X + N4_WQ); }
  float4 v = reinterpret_cast<const float4*>(src)[off];
  ushort4 o;
  o.x = f2bf(v.x); o.y = f2bf(v.y); o.z = f2bf(v.z); o.w = f2bf(v.w);
  reinterpret_cast<ushort4*>(dst)[off] = o;
}

// ---------------- GEMM: O[m][n] = sum_k A[m][k]*B[n][k] + bias[n] ----------------
// 2-phase double-buffered pipeline + XOR chunk-swizzle (chunk ^= row&7).
// 1D grid, XCD-aware mapping: each XCD owns a contiguous M-slab x all n-tiles.
template<int MODE, int BM, int NXB>
__global__ __launch_bounds__(256)
void gemm_bt(const unsigned short* __restrict__ A,
             const unsigned short* __restrict__ B,
             const float* __restrict__ bias,
             int M, int N, int K,
             unsigned short* __restrict__ Qo,
             unsigned short* __restrict__ Ko,
             unsigned short* __restrict__ Vo,
             float* __restrict__ Co) {
  __shared__ __align__(16) unsigned short As[2][BM * 64];
  __shared__ __align__(16) unsigned short Bs[2][128 * 64];
  const int FI = BM / 32;            // row-frags per wave
  const int t = threadIdx.x;
  const int l = t & 63;
  const int w = t >> 6;
  const int lo = l & 15, hi = l >> 4;
  const int wr = w >> 1, wc = w & 1;
  const int bid = blockIdx.x;
  const int xcd = bid & 7, idx = bid >> 3;
  const int ypx = (M / BM) >> 3;     // m-tiles per XCD
  const int m0 = (xcd * ypx + idx / NXB) * BM;
  const int n0 = (idx % NXB) * 128;

  f32x4 acc[FI][4] = {};

  auto stage = [&](int buf, int kt) {
    #pragma unroll
    for (int it = 0; it < BM / 32; ++it) {   // A: BM*8 chunks (16B each)
      int c = it * 256 + t;
      int row = c >> 3, cin = c & 7;
      int sw = cin ^ (row & 7);
      async16(A + (size_t)(m0 + row) * K + kt * 64 + sw * 8, &As[buf][c * 8]);
    }
    #pragma unroll
    for (int it = 0; it < 4; ++it) {         // B: 1024 chunks
      int c = it * 256 + t;
      int row = c >> 3, cin = c & 7;
      int sw = cin ^ (row & 7);
      async16(B + (size_t)(n0 + row) * K + kt * 64 + sw * 8, &Bs[buf][c * 8]);
    }
  };

  const int nkt = K >> 6;
  stage(0, 0);
  asm volatile("s_waitcnt vmcnt(0)" ::: "memory");
  __syncthreads();

  for (int kt = 0; kt < nkt; ++kt) {
    const int cur = kt & 1;
    if (kt + 1 < nkt) stage(cur ^ 1, kt + 1);   // prefetch overlaps compute

    __builtin_amdgcn_s_setprio(1);
    #pragma unroll
    for (int kk = 0; kk < 2; ++kk) {
      bf16x8 af[FI], bf[4];
      #pragma unroll
      for (int i = 0; i < FI; ++i) {
        int ra = wr * (BM / 2) + i * 16 + lo;        // ra&7 == lo&7
        int ch = (kk * 4 + hi) ^ (lo & 7);
        af[i] = *reinterpret_cast<const bf16x8*>(&As[cur][ra * 64 + ch * 8]);
      }
      #pragma unroll
      for (int j = 0; j < 4; ++j) {
        int rb = wc * 64 + j * 16 + lo;              // rb&7 == lo&7
        int ch = (kk * 4 + hi) ^ (lo & 7);
        bf[j] = *reinterpret_cast<const bf16x8*>(&Bs[cur][rb * 64 + ch * 8]);
      }
      #pragma unroll
      for (int i = 0; i < FI; ++i)
        #pragma unroll
        for (int j = 0; j < 4; ++j)
          acc[i][j] = __builtin_amdgcn_mfma_f32_16x16x32_bf16(af[i], bf[j], acc[i][j], 0, 0, 0);
    }
    __builtin_amdgcn_s_setprio(0);

    asm volatile("s_waitcnt vmcnt(0)" ::: "memory");  // next tile staged
    __syncthreads();
  }

  if (MODE == 0) {
    #pragma unroll
    for (int j = 0; j < 4; ++j) {
      int gcol = n0 + wc * 64 + j * 16 + lo;
      float bv = bias[gcol];
      int which = gcol >> 9;
      int h = (gcol >> 6) & 7;
      int d = gcol & 63;
      #pragma unroll
      for (int i = 0; i < FI; ++i) {
        int rbase = m0 + wr * (BM / 2) + i * 16 + hi * 4;
        int b = rbase >> 11;
        size_t bh = (size_t)(b * NH + h);
        if (which == 2) {
          ushort4 pk;
          pk.x = f2bf(acc[i][j][0] + bv);
          pk.y = f2bf(acc[i][j][1] + bv);
          pk.z = f2bf(acc[i][j][2] + bv);
          pk.w = f2bf(acc[i][j][3] + bv);
          int seq = rbase & 2047;
          *reinterpret_cast<ushort4*>(&Vo[(bh * HD + d) * SEQ + seq]) = pk;
        } else {
          #pragma unroll
          for (int e = 0; e < 4; ++e) {
            int seq = (rbase + e) & 2047;
            float v = acc[i][j][e] + bv;
            if (which == 0)
              // fold softmax scale AND log2(e) for exp2-based softmax
              Qo[(bh * SEQ + seq) * HD + d] = f2bf(v * 0.18033688f);
            else
              Ko[(bh * SEQ + seq) * HD + d] = f2bf(v);
          }
        }
      }
    }
  } else {
    #pragma unroll
    for (int j = 0; j < 4; ++j) {
      int gcol = n0 + wc * 64 + j * 16 + lo;
      float bv = bias[gcol];
      #pragma unroll
      for (int i = 0; i < FI; ++i) {
        int rbase = m0 + wr * (BM / 2) + i * 16 + hi * 4;
        #pragma unroll
        for (int e = 0; e < 4; ++e)
          Co[(size_t)(rbase + e) * N + gcol] = acc[i][j][e] + bv;
      }
    }
  }
}

// ---------------- flash attention (32x32 MFMA, K in LDS, V direct-to-reg) ------
// 1D grid 512, XCD-aware (R13): each XCD owns 4 bh -> K/V L2-resident.
// Block 512 = 8 waves = 4 q-groups x 2 kv-halves; 32 q-rows/wave.
// NEW vs R13: V fragments load global->register directly (per-lane 16B reads,
// L2 hits) -- removes half the LDS reads, half the staging, half the 4-way
// conflicts. K stays LDS-shared (double-buffered, XOR-swizzled).
// permlane32_swap semantics (CDNA4): swap(a,b) -> { [a_lo|b_lo], [a_hi|b_hi] }.
__global__ __launch_bounds__(512, 4)
void attn_kernel(const unsigned short* __restrict__ Q,   // [BH][SEQ][HD], pre-scaled
                 const unsigned short* __restrict__ Kk,  // [BH][SEQ][HD]
                 const unsigned short* __restrict__ Vt,  // [BH][HD][SEQ]
                 unsigned short* __restrict__ Ao) {      // [BB][SEQ][ED]
  // 64KB block: Ks = [half][buf] 4x 8KB (first 32KB); combine scratch = all 64KB
  __shared__ __align__(16) unsigned short smem[32768];
  auto KsP = [&](int half, int buf) { return &smem[(half * 2 + buf) * 4096]; };
  const int t = threadIdx.x;
  const int l = t & 63;
  const int wid = t >> 6;            // 0..7
  const int qg = wid & 3;            // q-group (4 x 32 rows)
  const int kvh = wid >> 2;          // kv half (0: seq 0..1023, 1: 1024..2047)
  const int l31 = l & 31, lh = l >> 5;
  const int bid = blockIdx.x;
  const int xcd = bid & 7, idx = bid >> 3;
  const int bh = xcd * 4 + (idx >> 4);
  const int q0 = (idx & 15) * 128;
  const int b = bh >> 3, h = bh & 7;

  // Q B-frags (col=q=l31, k=ks*16+lh*8+j)
  bf16x8 qf[4];
  #pragma unroll
  for (int ks = 0; ks < 4; ++ks)
    qf[ks] = *reinterpret_cast<const bf16x8*>(
        &Q[((size_t)bh * SEQ + q0 + qg * 32 + l31) * HD + ks * 16 + lh * 8]);

  f32x16 o0 = {}, o1 = {}, osum = {};
  const __bf16 one1 = (__bf16)1.0f;
  const bf16x8 ones = {one1, one1, one1, one1, one1, one1, one1, one1};

  // V fragment base addresses (direct global reads; L2-resident via XCD map)
  const unsigned short* vbase0 = &Vt[((size_t)bh * HD + l31) * SEQ];        // d=l31
  const unsigned short* vbase1 = &Vt[((size_t)bh * HD + 32 + l31) * SEQ];   // d=32+l31

  // stage K tile kt (0..15) of BOTH halves: threads 0-255 -> half0, rest half1
  auto stage = [&](int buf, int kt) {
    const int half = t >> 8;
    const int tt = t & 255;
    const int sbase = half * 1024 + kt * 64;
    unsigned short* kd = KsP(half, buf);
    #pragma unroll
    for (int it = 0; it < 2; ++it) {   // K: 512 chunks (16B) per half
      int c = it * 256 + tt;
      int row = c >> 3, cin = c & 7;
      int sw = cin ^ (row & 7);
      async16(&Kk[((size_t)bh * SEQ + sbase + row) * HD + sw * 8], kd + c * 8);
    }
  };

  auto tile = [&](int cur, int kt) {
    // V direct-to-reg for THIS tile: 8 x 16B loads, hidden under QK+exp2
    const int sb = kvh * 1024 + kt * 64;
    bf16x8 v0[4], v1[4];
    #pragma unroll
    for (int ss = 0; ss < 4; ++ss) {
      int so = sb + ss * 16 + lh * 8;
      v0[ss] = *reinterpret_cast<const bf16x8*>(vbase0 + so);
      v1[ss] = *reinterpret_cast<const bf16x8*>(vbase1 + so);
    }

    if (kt + 1 < 16) stage(cur ^ 1, kt + 1);   // K prefetch overlaps compute
    const unsigned short* kp = KsP(kvh, cur);

    #pragma unroll
    for (int kn = 0; kn < 2; ++kn) {   // 2 independent 32-seq chunks
      // S^T chunk: s[r] = S[q=l31][seq = kn*32 + (r&3)+8*(r>>2)+4*lh]
      f32x16 s = {};
      __builtin_amdgcn_s_setprio(1);
      #pragma unroll
      for (int ks = 0; ks < 4; ++ks) {
        int row = kn * 32 + l31;       // row&7 == l31&7
        int ch = ((ks * 2 + lh) ^ (l31 & 7)) * 8;
        bf16x8 kf = *reinterpret_cast<const bf16x8*>(&kp[row * 64 + ch]);
        s = __builtin_amdgcn_mfma_f32_32x32x16_bf16(kf, qf[ks], s, 0, 0, 0);
      }
      __builtin_amdgcn_s_setprio(0);

      #pragma unroll
      for (int i = 0; i < 16; ++i) s[i] = __builtin_amdgcn_exp2f(s[i]);

      #pragma unroll
      for (int hs = 0; hs < 2; ++hs) {
        unsigned int w0 = cvtpk(s[8 * hs + 0], s[8 * hs + 1]);
        unsigned int w1 = cvtpk(s[8 * hs + 2], s[8 * hs + 3]);
        unsigned int w2 = cvtpk(s[8 * hs + 4], s[8 * hs + 5]);
        unsigned int w3 = cvtpk(s[8 * hs + 6], s[8 * hs + 7]);
        i32x2 r0 = __builtin_amdgcn_permlane32_swap((int)w0, (int)w2, false, false);
        i32x2 r1 = __builtin_amdgcn_permlane32_swap((int)w1, (int)w3, false, false);
        u32x4 fw = {(unsigned int)r0.x, (unsigned int)r1.x,
                    (unsigned int)r0.y, (unsigned int)r1.y};
        bf16x8 pf = __builtin_bit_cast(bf16x8, fw);

        int ss = kn * 2 + hs;          // 16-seq step within the 64-tile (0..3)
        __builtin_amdgcn_s_setprio(1);
        osum = __builtin_amdgcn_mfma_f32_32x32x16_bf16(pf, ones, osum, 0, 0, 0);
        o0 = __builtin_amdgcn_mfma_f32_32x32x16_bf16(pf, v0[ss], o0, 0, 0, 0);
        o1 = __builtin_amdgcn_mfma_f32_32x32x16_bf16(pf, v1[ss], o1, 0, 0, 0);
        __builtin_amdgcn_s_setprio(0);
      }
    }

    asm volatile("s_waitcnt vmcnt(0)" ::: "memory");  // K stage complete
    __syncthreads();
  };

  stage(0, 0);
  asm volatile("s_waitcnt vmcnt(0)" ::: "memory");
  __syncthreads();

  for (int k2 = 0; k2 < 8; ++k2) {
    tile(0, 2 * k2);
    tile(1, 2 * k2 + 1);
  }

  // ---- combine the two kv-halves (simple addition; no-max-shift softmax) ----
  // scratch: (qg*64+l) slots of 64 floats (16 chunks of 16B, 12 used),
  // chunk-XOR swizzled (c&7 ^ l&7).
  float* lds = reinterpret_cast<float*>(&smem[0]);
  const int slot = qg * 64 + l;
  auto coff = [&](int c) {
    return (size_t)slot * 64 + (((c & ~7) | ((c & 7) ^ (l & 7))) << 2);
  };
  if (kvh == 1) {
    #pragma unroll
    for (int c = 0; c < 4; ++c) {
      *reinterpret_cast<f32x4*>(lds + coff(c))     = f32x4{o0[4*c], o0[4*c+1], o0[4*c+2], o0[4*c+3]};
      *reinterpret_cast<f32x4*>(lds + coff(c + 4)) = f32x4{o1[4*c], o1[4*c+1], o1[4*c+2], o1[4*c+3]};
      *reinterpret_cast<f32x4*>(lds + coff(c + 8)) = f32x4{osum[4*c], osum[4*c+1], osum[4*c+2], osum[4*c+3]};
    }
  }
  __syncthreads();
  if (kvh == 0) {
    #pragma unroll
    for (int c = 0; c < 4; ++c) {
      f32x4 a0 = *reinterpret_cast<const f32x4*>(lds + coff(c));
      f32x4 a1 = *reinterpret_cast<const f32x4*>(lds + coff(c + 4));
      f32x4 a2 = *reinterpret_cast<const f32x4*>(lds + coff(c + 8));
      #pragma unroll
      for (int e = 0; e < 4; ++e) {
        o0[4*c+e] += a0[e]; o1[4*c+e] += a1[e]; osum[4*c+e] += a2[e];
      }
    }

    // write: O D-layout col=d=l31(+32), row q=(r&3)+8*(r>>2)+4*lh
    #pragma unroll
    for (int r = 0; r < 16; ++r) {
      int qoff = (r & 3) + 8 * (r >> 2) + 4 * lh;
      int seq = q0 + qg * 32 + qoff;
      float inv = 1.f / osum[r];
      size_t base2 = ((size_t)b * SEQ + seq) * ED + h * HD;
      Ao[base2 + l31]      = f2bf(o0[r] * inv);
      Ao[base2 + 32 + l31] = f2bf(o1[r] * inv);
    }
  }
}

extern "C" void kernel_launch(void* const* d_in, const int* in_sizes, int n_in,
                              void* d_out, int out_size, void* d_ws, size_t ws_size,
                              hipStream_t stream) {
  const float* x      = (const float*)d_in[0];
  const float* qkv_w  = (const float*)d_in[1];
  const float* qkv_b  = (const float*)d_in[2];
  const float* proj_w = (const float*)d_in[3];
  const float* proj_b = (const float*)d_in[4];
  float* out = (float*)d_out;

  char* ws = (char*)d_ws;
  unsigned short* xb = (unsigned short*)(ws);                 // 8 MB
  unsigned short* wq = (unsigned short*)(ws + 8388608);       // 1.5 MB
  unsigned short* wp = (unsigned short*)(ws + 9961472);       // 0.5 MB
  unsigned short* Q  = (unsigned short*)(ws + 10485760);      // 8 MB
  unsigned short* Kb = (unsigned short*)(ws + 18874368);      // 8 MB
  unsigned short* Vt = (unsigned short*)(ws + 27262976);      // 8 MB
  unsigned short* Ao = (unsigned short*)(ws + 35651584);      // 8 MB  (total 42 MB)

  // single fused fp32->bf16 convert
  cvt_all<<<(N4_X + N4_WQ + N4_WP + 255) / 256, 256, 0, stream>>>(
      x, qkv_w, proj_w, xb, wq, wp);

  // QKV projection: (8192 x 512) @ (1536 x 512)^T, BM=64, 1536 blocks (XCD-mapped)
  gemm_bt<0, 64, 12><<<1536, 256, 0, stream>>>(xb, wq, qkv_b, MTOT, 3 * ED, ED, Q, Kb, Vt, nullptr);

  // flash attention: 512 blocks (XCD-mapped), 8 waves (4 qg x 2 kv-halves)
  attn_kernel<<<512, 512, 0, stream>>>(Q, Kb, Vt, Ao);

  // output projection: (8192 x 512) @ (512 x 512)^T, BM=64, 512 blocks (XCD-mapped)
  gemm_bt<1, 64, 4><<<512, 256, 0, stream>>>(Ao, wp, proj_b, MTOT, ED, ED, nullptr, nullptr, nullptr, out);
}

// Round 15
// 133.404 us; speedup vs baseline: 1.4143x; 1.4143x over previous
//
#include <hip/hip_runtime.h>

#define ED 512
#define NH 8
#define HD 64
#define BB 4
#define SEQ 2048
#define MTOT (BB*SEQ)   // 8192

typedef float f32x4 __attribute__((ext_vector_type(4)));
typedef float f32x16 __attribute__((ext_vector_type(16)));
typedef __bf16 bf16x8 __attribute__((ext_vector_type(8)));
typedef int i32x2 __attribute__((ext_vector_type(2)));
typedef unsigned int u32x4 __attribute__((ext_vector_type(4)));

__device__ __forceinline__ unsigned short f2bf(float f) {
  unsigned int u = __float_as_uint(f);
  u += 0x7FFFu + ((u >> 16) & 1u);
  return (unsigned short)(u >> 16);
}

__device__ __forceinline__ unsigned int cvtpk(float lo, float hi) {
  unsigned int r;
  asm volatile("v_cvt_pk_bf16_f32 %0, %1, %2" : "=v"(r) : "v"(lo), "v"(hi));
  return r;
}

__device__ __forceinline__ void async16(const void* g, void* l) {
  auto gp = (const __attribute__((address_space(1))) unsigned int*)(uintptr_t)(g);
  auto lp = (__attribute__((address_space(3))) unsigned int*)(uintptr_t)(l);
  __builtin_amdgcn_global_load_lds(gp, lp, 16, 0, 0);
}

// ---------------- fused fp32 -> bf16 convert (x, qkv_w, proj_w in one launch) ----
#define N4_X   1048576   // (4*2048*512)/4
#define N4_WQ  196608    // (3*512*512)/4
#define N4_WP  65536     // (512*512)/4
__global__ void cvt_all(const float* __restrict__ x,
                        const float* __restrict__ wq_in,
                        const float* __restrict__ wp_in,
                        unsigned short* __restrict__ xb,
                        unsigned short* __restrict__ wq,
                        unsigned short* __restrict__ wp) {
  int i = blockIdx.x * blockDim.x + threadIdx.x;
  const float* src; unsigned short* dst; int off;
  if (i < N4_X)              { src = x;     dst = xb; off = i; }
  else if (i < N4_X + N4_WQ) { src = wq_in; dst = wq; off = i - N4_X; }
  else                       { src = wp_in; dst = wp; off = i - (N4_X + N4_WQ); }
  float4 v = reinterpret_cast<const float4*>(src)[off];
  ushort4 o;
  o.x = f2bf(v.x); o.y = f2bf(v.y); o.z = f2bf(v.z); o.w = f2bf(v.w);
  reinterpret_cast<ushort4*>(dst)[off] = o;
}

// ---------------- GEMM: O[m][n] = sum_k A[m][k]*B[n][k] + bias[n] ----------------
// 2-phase double-buffered pipeline + XOR chunk-swizzle (chunk ^= row&7).
// 1D grid, XCD-aware mapping: each XCD owns a contiguous M-slab x all n-tiles.
template<int MODE, int BM, int NXB>
__global__ __launch_bounds__(256)
void gemm_bt(const unsigned short* __restrict__ A,
             const unsigned short* __restrict__ B,
             const float* __restrict__ bias,
             int M, int N, int K,
             unsigned short* __restrict__ Qo,
             unsigned short* __restrict__ Ko,
             unsigned short* __restrict__ Vo,
             float* __restrict__ Co) {
  __shared__ __align__(16) unsigned short As[2][BM * 64];
  __shared__ __align__(16) unsigned short Bs[2][128 * 64];
  const int FI = BM / 32;            // row-frags per wave
  const int t = threadIdx.x;
  const int l = t & 63;
  const int w = t >> 6;
  const int lo = l & 15, hi = l >> 4;
  const int wr = w >> 1, wc = w & 1;
  const int bid = blockIdx.x;
  const int xcd = bid & 7, idx = bid >> 3;
  const int ypx = (M / BM) >> 3;     // m-tiles per XCD
  const int m0 = (xcd * ypx + idx / NXB) * BM;
  const int n0 = (idx % NXB) * 128;

  f32x4 acc[FI][4] = {};

  auto stage = [&](int buf, int kt) {
    #pragma unroll
    for (int it = 0; it < BM / 32; ++it) {   // A: BM*8 chunks (16B each)
      int c = it * 256 + t;
      int row = c >> 3, cin = c & 7;
      int sw = cin ^ (row & 7);
      async16(A + (size_t)(m0 + row) * K + kt * 64 + sw * 8, &As[buf][c * 8]);
    }
    #pragma unroll
    for (int it = 0; it < 4; ++it) {         // B: 1024 chunks
      int c = it * 256 + t;
      int row = c >> 3, cin = c & 7;
      int sw = cin ^ (row & 7);
      async16(B + (size_t)(n0 + row) * K + kt * 64 + sw * 8, &Bs[buf][c * 8]);
    }
  };

  const int nkt = K >> 6;
  stage(0, 0);
  asm volatile("s_waitcnt vmcnt(0)" ::: "memory");
  __syncthreads();

  for (int kt = 0; kt < nkt; ++kt) {
    const int cur = kt & 1;
    if (kt + 1 < nkt) stage(cur ^ 1, kt + 1);   // prefetch overlaps compute

    __builtin_amdgcn_s_setprio(1);
    #pragma unroll
    for (int kk = 0; kk < 2; ++kk) {
      bf16x8 af[FI], bf[4];
      #pragma unroll
      for (int i = 0; i < FI; ++i) {
        int ra = wr * (BM / 2) + i * 16 + lo;        // ra&7 == lo&7
        int ch = (kk * 4 + hi) ^ (lo & 7);
        af[i] = *reinterpret_cast<const bf16x8*>(&As[cur][ra * 64 + ch * 8]);
      }
      #pragma unroll
      for (int j = 0; j < 4; ++j) {
        int rb = wc * 64 + j * 16 + lo;              // rb&7 == lo&7
        int ch = (kk * 4 + hi) ^ (lo & 7);
        bf[j] = *reinterpret_cast<const bf16x8*>(&Bs[cur][rb * 64 + ch * 8]);
      }
      #pragma unroll
      for (int i = 0; i < FI; ++i)
        #pragma unroll
        for (int j = 0; j < 4; ++j)
          acc[i][j] = __builtin_amdgcn_mfma_f32_16x16x32_bf16(af[i], bf[j], acc[i][j], 0, 0, 0);
    }
    __builtin_amdgcn_s_setprio(0);

    asm volatile("s_waitcnt vmcnt(0)" ::: "memory");  // next tile staged
    __syncthreads();
  }

  if (MODE == 0) {
    #pragma unroll
    for (int j = 0; j < 4; ++j) {
      int gcol = n0 + wc * 64 + j * 16 + lo;
      float bv = bias[gcol];
      int which = gcol >> 9;
      int h = (gcol >> 6) & 7;
      int d = gcol & 63;
      #pragma unroll
      for (int i = 0; i < FI; ++i) {
        int rbase = m0 + wr * (BM / 2) + i * 16 + hi * 4;
        int b = rbase >> 11;
        size_t bh = (size_t)(b * NH + h);
        if (which == 2) {
          ushort4 pk;
          pk.x = f2bf(acc[i][j][0] + bv);
          pk.y = f2bf(acc[i][j][1] + bv);
          pk.z = f2bf(acc[i][j][2] + bv);
          pk.w = f2bf(acc[i][j][3] + bv);
          int seq = rbase & 2047;
          *reinterpret_cast<ushort4*>(&Vo[(bh * HD + d) * SEQ + seq]) = pk;
        } else {
          #pragma unroll
          for (int e = 0; e < 4; ++e) {
            int seq = (rbase + e) & 2047;
            float v = acc[i][j][e] + bv;
            if (which == 0)
              // fold softmax scale AND log2(e) for exp2-based softmax
              Qo[(bh * SEQ + seq) * HD + d] = f2bf(v * 0.18033688f);
            else
              Ko[(bh * SEQ + seq) * HD + d] = f2bf(v);
          }
        }
      }
    }
  } else {
    #pragma unroll
    for (int j = 0; j < 4; ++j) {
      int gcol = n0 + wc * 64 + j * 16 + lo;
      float bv = bias[gcol];
      #pragma unroll
      for (int i = 0; i < FI; ++i) {
        int rbase = m0 + wr * (BM / 2) + i * 16 + hi * 4;
        #pragma unroll
        for (int e = 0; e < 4; ++e)
          Co[(size_t)(rbase + e) * N + gcol] = acc[i][j][e] + bv;
      }
    }
  }
}

// ---------------- flash attention (32x32 MFMA, K in LDS, V direct-to-reg) ------
// 1D grid 512, XCD-aware: each XCD owns 4 bh -> K/V L2-resident.
// Block 512 = 8 waves = 4 q-groups x 2 kv-halves; 32 q-rows/wave.
// V fragments load global->register PER 32-SEQ CHUNK, placed between that
// chunk's QK MFMAs and its exp2 block: latency hidden by the exp2 chain,
// live range ends inside the same kn iteration (no values cross a barrier --
// the R14 spill is structurally impossible). K stays LDS (dbuf, XOR-swizzle).
// permlane32_swap semantics (CDNA4): swap(a,b) -> { [a_lo|b_lo], [a_hi|b_hi] }.
__global__ __launch_bounds__(512, 4)
void attn_kernel(const unsigned short* __restrict__ Q,   // [BH][SEQ][HD], pre-scaled
                 const unsigned short* __restrict__ Kk,  // [BH][SEQ][HD]
                 const unsigned short* __restrict__ Vt,  // [BH][HD][SEQ]
                 unsigned short* __restrict__ Ao) {      // [BB][SEQ][ED]
  // 64KB block: Ks = [half][buf] 4x 8KB (first 32KB); combine scratch = all 64KB
  __shared__ __align__(16) unsigned short smem[32768];
  auto KsP = [&](int half, int buf) { return &smem[(half * 2 + buf) * 4096]; };
  const int t = threadIdx.x;
  const int l = t & 63;
  const int wid = t >> 6;            // 0..7
  const int qg = wid & 3;            // q-group (4 x 32 rows)
  const int kvh = wid >> 2;          // kv half (0: seq 0..1023, 1: 1024..2047)
  const int l31 = l & 31, lh = l >> 5;
  const int bid = blockIdx.x;
  const int xcd = bid & 7, idx = bid >> 3;
  const int bh = xcd * 4 + (idx >> 4);
  const int q0 = (idx & 15) * 128;
  const int b = bh >> 3, h = bh & 7;

  // Q B-frags (col=q=l31, k=ks*16+lh*8+j)
  bf16x8 qf[4];
  #pragma unroll
  for (int ks = 0; ks < 4; ++ks)
    qf[ks] = *reinterpret_cast<const bf16x8*>(
        &Q[((size_t)bh * SEQ + q0 + qg * 32 + l31) * HD + ks * 16 + lh * 8]);

  f32x16 o0 = {}, o1 = {}, osum = {};
  const __bf16 one1 = (__bf16)1.0f;
  const bf16x8 ones = {one1, one1, one1, one1, one1, one1, one1, one1};

  // V fragment base addresses (direct global reads; L2-resident via XCD map)
  const unsigned short* vbase0 = &Vt[((size_t)bh * HD + l31) * SEQ];        // d=l31
  const unsigned short* vbase1 = &Vt[((size_t)bh * HD + 32 + l31) * SEQ];   // d=32+l31

  // stage K tile kt (0..15) of BOTH halves: threads 0-255 -> half0, rest half1
  auto stage = [&](int buf, int kt) {
    const int half = t >> 8;
    const int tt = t & 255;
    const int sbase = half * 1024 + kt * 64;
    unsigned short* kd = KsP(half, buf);
    #pragma unroll
    for (int it = 0; it < 2; ++it) {   // K: 512 chunks (16B) per half
      int c = it * 256 + tt;
      int row = c >> 3, cin = c & 7;
      int sw = cin ^ (row & 7);
      async16(&Kk[((size_t)bh * SEQ + sbase + row) * HD + sw * 8], kd + c * 8);
    }
  };

  auto tile = [&](int cur, int kt) {
    if (kt + 1 < 16) stage(cur ^ 1, kt + 1);   // K prefetch overlaps compute
    const unsigned short* kp = KsP(kvh, cur);
    const int sb = kvh * 1024 + kt * 64;

    #pragma unroll
    for (int kn = 0; kn < 2; ++kn) {   // 2 independent 32-seq chunks
      // S^T chunk: s[r] = S[q=l31][seq = kn*32 + (r&3)+8*(r>>2)+4*lh]
      f32x16 s = {};
      __builtin_amdgcn_s_setprio(1);
      #pragma unroll
      for (int ks = 0; ks < 4; ++ks) {
        int row = kn * 32 + l31;       // row&7 == l31&7
        int ch = ((ks * 2 + lh) ^ (l31 & 7)) * 8;
        bf16x8 kf = *reinterpret_cast<const bf16x8*>(&kp[row * 64 + ch]);
        s = __builtin_amdgcn_mfma_f32_32x32x16_bf16(kf, qf[ks], s, 0, 0, 0);
      }
      __builtin_amdgcn_s_setprio(0);

      // V for THIS chunk only (2 pairs, 64B): latency hidden by exp2 chain,
      // dead before the next barrier -> no spill pressure.
      bf16x8 v0[2], v1[2];
      #pragma unroll
      for (int hs = 0; hs < 2; ++hs) {
        int so = sb + (kn * 2 + hs) * 16 + lh * 8;
        v0[hs] = *reinterpret_cast<const bf16x8*>(vbase0 + so);
        v1[hs] = *reinterpret_cast<const bf16x8*>(vbase1 + so);
      }

      #pragma unroll
      for (int i = 0; i < 16; ++i) s[i] = __builtin_amdgcn_exp2f(s[i]);

      #pragma unroll
      for (int hs = 0; hs < 2; ++hs) {
        unsigned int w0 = cvtpk(s[8 * hs + 0], s[8 * hs + 1]);
        unsigned int w1 = cvtpk(s[8 * hs + 2], s[8 * hs + 3]);
        unsigned int w2 = cvtpk(s[8 * hs + 4], s[8 * hs + 5]);
        unsigned int w3 = cvtpk(s[8 * hs + 6], s[8 * hs + 7]);
        i32x2 r0 = __builtin_amdgcn_permlane32_swap((int)w0, (int)w2, false, false);
        i32x2 r1 = __builtin_amdgcn_permlane32_swap((int)w1, (int)w3, false, false);
        u32x4 fw = {(unsigned int)r0.x, (unsigned int)r1.x,
                    (unsigned int)r0.y, (unsigned int)r1.y};
        bf16x8 pf = __builtin_bit_cast(bf16x8, fw);

        __builtin_amdgcn_s_setprio(1);
        osum = __builtin_amdgcn_mfma_f32_32x32x16_bf16(pf, ones, osum, 0, 0, 0);
        o0 = __builtin_amdgcn_mfma_f32_32x32x16_bf16(pf, v0[hs], o0, 0, 0, 0);
        o1 = __builtin_amdgcn_mfma_f32_32x32x16_bf16(pf, v1[hs], o1, 0, 0, 0);
        __builtin_amdgcn_s_setprio(0);
      }
    }

    asm volatile("s_waitcnt vmcnt(0)" ::: "memory");  // K stage complete
    __syncthreads();
  };

  stage(0, 0);
  asm volatile("s_waitcnt vmcnt(0)" ::: "memory");
  __syncthreads();

  for (int k2 = 0; k2 < 8; ++k2) {
    tile(0, 2 * k2);
    tile(1, 2 * k2 + 1);
  }

  // ---- combine the two kv-halves (simple addition; no-max-shift softmax) ----
  // scratch: (qg*64+l) slots of 64 floats (16 chunks of 16B, 12 used),
  // chunk-XOR swizzled (c&7 ^ l&7).
  float* lds = reinterpret_cast<float*>(&smem[0]);
  const int slot = qg * 64 + l;
  auto coff = [&](int c) {
    return (size_t)slot * 64 + (((c & ~7) | ((c & 7) ^ (l & 7))) << 2);
  };
  if (kvh == 1) {
    #pragma unroll
    for (int c = 0; c < 4; ++c) {
      *reinterpret_cast<f32x4*>(lds + coff(c))     = f32x4{o0[4*c], o0[4*c+1], o0[4*c+2], o0[4*c+3]};
      *reinterpret_cast<f32x4*>(lds + coff(c + 4)) = f32x4{o1[4*c], o1[4*c+1], o1[4*c+2], o1[4*c+3]};
      *reinterpret_cast<f32x4*>(lds + coff(c + 8)) = f32x4{osum[4*c], osum[4*c+1], osum[4*c+2], osum[4*c+3]};
    }
  }
  __syncthreads();
  if (kvh == 0) {
    #pragma unroll
    for (int c = 0; c < 4; ++c) {
      f32x4 a0 = *reinterpret_cast<const f32x4*>(lds + coff(c));
      f32x4 a1 = *reinterpret_cast<const f32x4*>(lds + coff(c + 4));
      f32x4 a2 = *reinterpret_cast<const f32x4*>(lds + coff(c + 8));
      #pragma unroll
      for (int e = 0; e < 4; ++e) {
        o0[4*c+e] += a0[e]; o1[4*c+e] += a1[e]; osum[4*c+e] += a2[e];
      }
    }

    // write: O D-layout col=d=l31(+32), row q=(r&3)+8*(r>>2)+4*lh
    #pragma unroll
    for (int r = 0; r < 16; ++r) {
      int qoff = (r & 3) + 8 * (r >> 2) + 4 * lh;
      int seq = q0 + qg * 32 + qoff;
      float inv = 1.f / osum[r];
      size_t base2 = ((size_t)b * SEQ + seq) * ED + h * HD;
      Ao[base2 + l31]      = f2bf(o0[r] * inv);
      Ao[base2 + 32 + l31] = f2bf(o1[r] * inv);
    }
  }
}

extern "C" void kernel_launch(void* const* d_in, const int* in_sizes, int n_in,
                              void* d_out, int out_size, void* d_ws, size_t ws_size,
                              hipStream_t stream) {
  const float* x      = (const float*)d_in[0];
  const float* qkv_w  = (const float*)d_in[1];
  const float* qkv_b  = (const float*)d_in[2];
  const float* proj_w = (const float*)d_in[3];
  const float* proj_b = (const float*)d_in[4];
  float* out = (float*)d_out;

  char* ws = (char*)d_ws;
  unsigned short* xb = (unsigned short*)(ws);                 // 8 MB
  unsigned short* wq = (unsigned short*)(ws + 8388608);       // 1.5 MB
  unsigned short* wp = (unsigned short*)(ws + 9961472);       // 0.5 MB
  unsigned short* Q  = (unsigned short*)(ws + 10485760);      // 8 MB
  unsigned short* Kb = (unsigned short*)(ws + 18874368);      // 8 MB
  unsigned short* Vt = (unsigned short*)(ws + 27262976);      // 8 MB
  unsigned short* Ao = (unsigned short*)(ws + 35651584);      // 8 MB  (total 42 MB)

  // single fused fp32->bf16 convert
  cvt_all<<<(N4_X + N4_WQ + N4_WP + 255) / 256, 256, 0, stream>>>(
      x, qkv_w, proj_w, xb, wq, wp);

  // QKV projection: (8192 x 512) @ (1536 x 512)^T, BM=64, 1536 blocks (XCD-mapped)
  gemm_bt<0, 64, 12><<<1536, 256, 0, stream>>>(xb, wq, qkv_b, MTOT, 3 * ED, ED, Q, Kb, Vt, nullptr);

  // flash attention: 512 blocks (XCD-mapped), 8 waves (4 qg x 2 kv-halves)
  attn_kernel<<<512, 512, 0, stream>>>(Q, Kb, Vt, Ao);

  // output projection: (8192 x 512) @ (512 x 512)^T, BM=64, 512 blocks (XCD-mapped)
  gemm_bt<1, 64, 4><<<512, 256, 0, stream>>>(Ao, wp, proj_b, MTOT, ED, ED, nullptr, nullptr, nullptr, out);
}

// Round 16
// 80.927 us; speedup vs baseline: 2.3313x; 1.6484x over previous
//
#include <hip/hip_runtime.h>

#define ED 512
#define NH 8
#define HD 64
#define BB 4
#define SEQ 2048
#define MTOT (BB*SEQ)   // 8192

typedef float f32x4 __attribute__((ext_vector_type(4)));
typedef float f32x16 __attribute__((ext_vector_type(16)));
typedef __bf16 bf16x8 __attribute__((ext_vector_type(8)));
typedef int i32x2 __attribute__((ext_vector_type(2)));
typedef unsigned int u32x4 __attribute__((ext_vector_type(4)));

__device__ __forceinline__ unsigned short f2bf(float f) {
  unsigned int u = __float_as_uint(f);
  u += 0x7FFFu + ((u >> 16) & 1u);
  return (unsigned short)(u >> 16);
}

__device__ __forceinline__ unsigned int cvtpk(float lo, float hi) {
  unsigned int r;
  asm volatile("v_cvt_pk_bf16_f32 %0, %1, %2" : "=v"(r) : "v"(lo), "v"(hi));
  return r;
}

__device__ __forceinline__ void async16(const void* g, void* l) {
  auto gp = (const __attribute__((address_space(1))) unsigned int*)(uintptr_t)(g);
  auto lp = (__attribute__((address_space(3))) unsigned int*)(uintptr_t)(l);
  __builtin_amdgcn_global_load_lds(gp, lp, 16, 0, 0);
}

// ---------------- fused fp32 -> bf16 convert (x, qkv_w, proj_w in one launch) ----
#define N4_X   1048576   // (4*2048*512)/4
#define N4_WQ  196608    // (3*512*512)/4
#define N4_WP  65536     // (512*512)/4
__global__ void cvt_all(const float* __restrict__ x,
                        const float* __restrict__ wq_in,
                        const float* __restrict__ wp_in,
                        unsigned short* __restrict__ xb,
                        unsigned short* __restrict__ wq,
                        unsigned short* __restrict__ wp) {
  int i = blockIdx.x * blockDim.x + threadIdx.x;
  const float* src; unsigned short* dst; int off;
  if (i < N4_X)              { src = x;     dst = xb; off = i; }
  else if (i < N4_X + N4_WQ) { src = wq_in; dst = wq; off = i - N4_X; }
  else                       { src = wp_in; dst = wp; off = i - (N4_X + N4_WQ); }
  float4 v = reinterpret_cast<const float4*>(src)[off];
  ushort4 o;
  o.x = f2bf(v.x); o.y = f2bf(v.y); o.z = f2bf(v.z); o.w = f2bf(v.w);
  reinterpret_cast<ushort4*>(dst)[off] = o;
}

// ---------------- GEMM: O[m][n] = sum_k A[m][k]*B[n][k] + bias[n] ----------------
// 2-phase double-buffered pipeline + XOR chunk-swizzle (chunk ^= row&7).
// 1D grid, XCD-aware mapping: each XCD owns a contiguous M-slab x all n-tiles.
template<int MODE, int BM, int NXB>
__global__ __launch_bounds__(256)
void gemm_bt(const unsigned short* __restrict__ A,
             const unsigned short* __restrict__ B,
             const float* __restrict__ bias,
             int M, int N, int K,
             unsigned short* __restrict__ Qo,
             unsigned short* __restrict__ Ko,
             unsigned short* __restrict__ Vo,
             float* __restrict__ Co) {
  __shared__ __align__(16) unsigned short As[2][BM * 64];
  __shared__ __align__(16) unsigned short Bs[2][128 * 64];
  const int FI = BM / 32;            // row-frags per wave
  const int t = threadIdx.x;
  const int l = t & 63;
  const int w = t >> 6;
  const int lo = l & 15, hi = l >> 4;
  const int wr = w >> 1, wc = w & 1;
  const int bid = blockIdx.x;
  const int xcd = bid & 7, idx = bid >> 3;
  const int ypx = (M / BM) >> 3;     // m-tiles per XCD
  const int m0 = (xcd * ypx + idx / NXB) * BM;
  const int n0 = (idx % NXB) * 128;

  f32x4 acc[FI][4] = {};

  auto stage = [&](int buf, int kt) {
    #pragma unroll
    for (int it = 0; it < BM / 32; ++it) {   // A: BM*8 chunks (16B each)
      int c = it * 256 + t;
      int row = c >> 3, cin = c & 7;
      int sw = cin ^ (row & 7);
      async16(A + (size_t)(m0 + row) * K + kt * 64 + sw * 8, &As[buf][c * 8]);
    }
    #pragma unroll
    for (int it = 0; it < 4; ++it) {         // B: 1024 chunks
      int c = it * 256 + t;
      int row = c >> 3, cin = c & 7;
      int sw = cin ^ (row & 7);
      async16(B + (size_t)(n0 + row) * K + kt * 64 + sw * 8, &Bs[buf][c * 8]);
    }
  };

  const int nkt = K >> 6;
  stage(0, 0);
  asm volatile("s_waitcnt vmcnt(0)" ::: "memory");
  __syncthreads();

  for (int kt = 0; kt < nkt; ++kt) {
    const int cur = kt & 1;
    if (kt + 1 < nkt) stage(cur ^ 1, kt + 1);   // prefetch overlaps compute

    __builtin_amdgcn_s_setprio(1);
    #pragma unroll
    for (int kk = 0; kk < 2; ++kk) {
      bf16x8 af[FI], bf[4];
      #pragma unroll
      for (int i = 0; i < FI; ++i) {
        int ra = wr * (BM / 2) + i * 16 + lo;        // ra&7 == lo&7
        int ch = (kk * 4 + hi) ^ (lo & 7);
        af[i] = *reinterpret_cast<const bf16x8*>(&As[cur][ra * 64 + ch * 8]);
      }
      #pragma unroll
      for (int j = 0; j < 4; ++j) {
        int rb = wc * 64 + j * 16 + lo;              // rb&7 == lo&7
        int ch = (kk * 4 + hi) ^ (lo & 7);
        bf[j] = *reinterpret_cast<const bf16x8*>(&Bs[cur][rb * 64 + ch * 8]);
      }
      #pragma unroll
      for (int i = 0; i < FI; ++i)
        #pragma unroll
        for (int j = 0; j < 4; ++j)
          acc[i][j] = __builtin_amdgcn_mfma_f32_16x16x32_bf16(af[i], bf[j], acc[i][j], 0, 0, 0);
    }
    __builtin_amdgcn_s_setprio(0);

    asm volatile("s_waitcnt vmcnt(0)" ::: "memory");  // next tile staged
    __syncthreads();
  }

  if (MODE == 0) {
    #pragma unroll
    for (int j = 0; j < 4; ++j) {
      int gcol = n0 + wc * 64 + j * 16 + lo;
      float bv = bias[gcol];
      int which = gcol >> 9;
      int h = (gcol >> 6) & 7;
      int d = gcol & 63;
      #pragma unroll
      for (int i = 0; i < FI; ++i) {
        int rbase = m0 + wr * (BM / 2) + i * 16 + hi * 4;
        int b = rbase >> 11;
        size_t bh = (size_t)(b * NH + h);
        if (which == 2) {
          ushort4 pk;
          pk.x = f2bf(acc[i][j][0] + bv);
          pk.y = f2bf(acc[i][j][1] + bv);
          pk.z = f2bf(acc[i][j][2] + bv);
          pk.w = f2bf(acc[i][j][3] + bv);
          int seq = rbase & 2047;
          *reinterpret_cast<ushort4*>(&Vo[(bh * HD + d) * SEQ + seq]) = pk;
        } else {
          #pragma unroll
          for (int e = 0; e < 4; ++e) {
            int seq = (rbase + e) & 2047;
            float v = acc[i][j][e] + bv;
            if (which == 0)
              // fold softmax scale AND log2(e) for exp2-based softmax
              Qo[(bh * SEQ + seq) * HD + d] = f2bf(v * 0.18033688f);
            else
              Ko[(bh * SEQ + seq) * HD + d] = f2bf(v);
          }
        }
      }
    }
  } else {
    #pragma unroll
    for (int j = 0; j < 4; ++j) {
      int gcol = n0 + wc * 64 + j * 16 + lo;
      float bv = bias[gcol];
      #pragma unroll
      for (int i = 0; i < FI; ++i) {
        int rbase = m0 + wr * (BM / 2) + i * 16 + hi * 4;
        #pragma unroll
        for (int e = 0; e < 4; ++e)
          Co[(size_t)(rbase + e) * N + gcol] = acc[i][j][e] + bv;
      }
    }
  }
}

// ---------------- flash attention (32x32 MFMA, in-block 2-way KV split) --------
// R13 configuration (proven best: attn 45.0us, total 81.0us).
// 1D grid 512, XCD-aware: each XCD owns 4 bh -> K/V slab (2MB) L2-resident.
// Block 512 = 8 waves = 4 q-groups x 2 kv-halves; 32 q-rows/wave; kv-halves
// stream their own 1024-seq range double-buffered; no-max-shift exp2 softmax;
// halves combine by ADDITION through chunk-XOR-swizzled LDS scratch.
// NOTE (R14/R15 lesson): at 16 waves/CU the unified reg budget is 128/wave and
// this kernel uses exactly 64 VGPR + 64 AGPR -- any extra live state (e.g.
// V-in-register) forces scratch spill. Do not add register pressure here.
// permlane32_swap semantics (CDNA4): swap(a,b) -> { [a_lo|b_lo], [a_hi|b_hi] }.
__global__ __launch_bounds__(512, 4)
void attn_kernel(const unsigned short* __restrict__ Q,   // [BH][SEQ][HD], pre-scaled
                 const unsigned short* __restrict__ Kk,  // [BH][SEQ][HD]
                 const unsigned short* __restrict__ Vt,  // [BH][HD][SEQ]
                 unsigned short* __restrict__ Ao) {      // [BB][SEQ][ED]
  // one 64KB block: Ks = [half][buf] 4x 8KB, then Vs = [half][buf] 4x 8KB
  __shared__ __align__(16) unsigned short smem[32768];
  auto KsP = [&](int half, int buf) { return &smem[(half * 2 + buf) * 4096]; };
  auto VsP = [&](int half, int buf) { return &smem[16384 + (half * 2 + buf) * 4096]; };
  const int t = threadIdx.x;
  const int l = t & 63;
  const int wid = t >> 6;            // 0..7
  const int qg = wid & 3;            // q-group (4 x 32 rows)
  const int kvh = wid >> 2;          // kv half (0: seq 0..1023, 1: 1024..2047)
  const int l31 = l & 31, lh = l >> 5;
  const int bid = blockIdx.x;
  const int xcd = bid & 7, idx = bid >> 3;
  const int bh = xcd * 4 + (idx >> 4);
  const int q0 = (idx & 15) * 128;
  const int b = bh >> 3, h = bh & 7;

  // Q B-frags (col=q=l31, k=ks*16+lh*8+j)
  bf16x8 qf[4];
  #pragma unroll
  for (int ks = 0; ks < 4; ++ks)
    qf[ks] = *reinterpret_cast<const bf16x8*>(
        &Q[((size_t)bh * SEQ + q0 + qg * 32 + l31) * HD + ks * 16 + lh * 8]);

  f32x16 o0 = {}, o1 = {}, osum = {};
  const __bf16 one1 = (__bf16)1.0f;
  const bf16x8 ones = {one1, one1, one1, one1, one1, one1, one1, one1};

  // stage tile kt (0..15) of BOTH halves: threads 0-255 -> half0, 256-511 -> half1
  auto stage = [&](int buf, int kt) {
    const int half = t >> 8;
    const int tt = t & 255;
    const int sbase = half * 1024 + kt * 64;
    unsigned short* kd = KsP(half, buf);
    unsigned short* vd = VsP(half, buf);
    #pragma unroll
    for (int it = 0; it < 2; ++it) {   // K: 512 chunks (16B) per half
      int c = it * 256 + tt;
      int row = c >> 3, cin = c & 7;
      int sw = cin ^ (row & 7);
      async16(&Kk[((size_t)bh * SEQ + sbase + row) * HD + sw * 8], kd + c * 8);
    }
    #pragma unroll
    for (int it = 0; it < 2; ++it) {   // V: 512 chunks per half, [d][seq64]
      int c = it * 256 + tt;
      int row = c >> 3, cin = c & 7;
      int sw = cin ^ (row & 7);
      async16(&Vt[((size_t)bh * HD + row) * SEQ + sbase + sw * 8], vd + c * 8);
    }
  };

  auto tile = [&](int cur, int kt) {
    if (kt + 1 < 16) stage(cur ^ 1, kt + 1);   // prefetch overlaps compute
    const unsigned short* kp = KsP(kvh, cur);
    const unsigned short* vp = VsP(kvh, cur);

    #pragma unroll
    for (int kn = 0; kn < 2; ++kn) {   // 2 independent 32-seq chunks
      // S^T chunk: s[r] = S[q=l31][seq = kn*32 + (r&3)+8*(r>>2)+4*lh]
      f32x16 s = {};
      __builtin_amdgcn_s_setprio(1);
      #pragma unroll
      for (int ks = 0; ks < 4; ++ks) {
        int row = kn * 32 + l31;       // row&7 == l31&7
        int ch = ((ks * 2 + lh) ^ (l31 & 7)) * 8;
        bf16x8 kf = *reinterpret_cast<const bf16x8*>(&kp[row * 64 + ch]);
        s = __builtin_amdgcn_mfma_f32_32x32x16_bf16(kf, qf[ks], s, 0, 0, 0);
      }
      __builtin_amdgcn_s_setprio(0);

      #pragma unroll
      for (int i = 0; i < 16; ++i) s[i] = __builtin_amdgcn_exp2f(s[i]);

      #pragma unroll
      for (int hs = 0; hs < 2; ++hs) {
        unsigned int w0 = cvtpk(s[8 * hs + 0], s[8 * hs + 1]);
        unsigned int w1 = cvtpk(s[8 * hs + 2], s[8 * hs + 3]);
        unsigned int w2 = cvtpk(s[8 * hs + 4], s[8 * hs + 5]);
        unsigned int w3 = cvtpk(s[8 * hs + 6], s[8 * hs + 7]);
        i32x2 r0 = __builtin_amdgcn_permlane32_swap((int)w0, (int)w2, false, false);
        i32x2 r1 = __builtin_amdgcn_permlane32_swap((int)w1, (int)w3, false, false);
        u32x4 fw = {(unsigned int)r0.x, (unsigned int)r1.x,
                    (unsigned int)r0.y, (unsigned int)r1.y};
        bf16x8 pf = __builtin_bit_cast(bf16x8, fw);

        int ss = kn * 2 + hs;          // 16-seq step within the 64-tile (0..3)
        int vch = ((ss * 2 + lh) ^ (l31 & 7)) * 8;
        __builtin_amdgcn_s_setprio(1);
        osum = __builtin_amdgcn_mfma_f32_32x32x16_bf16(pf, ones, osum, 0, 0, 0);
        bf16x8 vf0 = *reinterpret_cast<const bf16x8*>(&vp[l31 * 64 + vch]);
        bf16x8 vf1 = *reinterpret_cast<const bf16x8*>(&vp[(32 + l31) * 64 + vch]);
        o0 = __builtin_amdgcn_mfma_f32_32x32x16_bf16(pf, vf0, o0, 0, 0, 0);
        o1 = __builtin_amdgcn_mfma_f32_32x32x16_bf16(pf, vf1, o1, 0, 0, 0);
        __builtin_amdgcn_s_setprio(0);
      }
    }

    asm volatile("s_waitcnt vmcnt(0)" ::: "memory");  // next-tile stage complete
    __syncthreads();
  };

  stage(0, 0);
  asm volatile("s_waitcnt vmcnt(0)" ::: "memory");
  __syncthreads();

  for (int k2 = 0; k2 < 8; ++k2) {
    tile(0, 2 * k2);
    tile(1, 2 * k2 + 1);
  }

  // ---- combine the two kv-halves (simple addition; no-max-shift softmax) ----
  // scratch: (qg*64+l) slots of 64 floats (16 chunks of 16B, 12 used),
  // chunk-XOR swizzled (c&7 ^ l&7).
  float* lds = reinterpret_cast<float*>(&smem[0]);
  const int slot = qg * 64 + l;
  auto coff = [&](int c) {
    return (size_t)slot * 64 + (((c & ~7) | ((c & 7) ^ (l & 7))) << 2);
  };
  if (kvh == 1) {
    #pragma unroll
    for (int c = 0; c < 4; ++c) {
      *reinterpret_cast<f32x4*>(lds + coff(c))     = f32x4{o0[4*c], o0[4*c+1], o0[4*c+2], o0[4*c+3]};
      *reinterpret_cast<f32x4*>(lds + coff(c + 4)) = f32x4{o1[4*c], o1[4*c+1], o1[4*c+2], o1[4*c+3]};
      *reinterpret_cast<f32x4*>(lds + coff(c + 8)) = f32x4{osum[4*c], osum[4*c+1], osum[4*c+2], osum[4*c+3]};
    }
  }
  __syncthreads();
  if (kvh == 0) {
    #pragma unroll
    for (int c = 0; c < 4; ++c) {
      f32x4 a0 = *reinterpret_cast<const f32x4*>(lds + coff(c));
      f32x4 a1 = *reinterpret_cast<const f32x4*>(lds + coff(c + 4));
      f32x4 a2 = *reinterpret_cast<const f32x4*>(lds + coff(c + 8));
      #pragma unroll
      for (int e = 0; e < 4; ++e) {
        o0[4*c+e] += a0[e]; o1[4*c+e] += a1[e]; osum[4*c+e] += a2[e];
      }
    }

    // write: O D-layout col=d=l31(+32), row q=(r&3)+8*(r>>2)+4*lh
    #pragma unroll
    for (int r = 0; r < 16; ++r) {
      int qoff = (r & 3) + 8 * (r >> 2) + 4 * lh;
      int seq = q0 + qg * 32 + qoff;
      float inv = 1.f / osum[r];
      size_t base2 = ((size_t)b * SEQ + seq) * ED + h * HD;
      Ao[base2 + l31]      = f2bf(o0[r] * inv);
      Ao[base2 + 32 + l31] = f2bf(o1[r] * inv);
    }
  }
}

extern "C" void kernel_launch(void* const* d_in, const int* in_sizes, int n_in,
                              void* d_out, int out_size, void* d_ws, size_t ws_size,
                              hipStream_t stream) {
  const float* x      = (const float*)d_in[0];
  const float* qkv_w  = (const float*)d_in[1];
  const float* qkv_b  = (const float*)d_in[2];
  const float* proj_w = (const float*)d_in[3];
  const float* proj_b = (const float*)d_in[4];
  float* out = (float*)d_out;

  char* ws = (char*)d_ws;
  unsigned short* xb = (unsigned short*)(ws);                 // 8 MB
  unsigned short* wq = (unsigned short*)(ws + 8388608);       // 1.5 MB
  unsigned short* wp = (unsigned short*)(ws + 9961472);       // 0.5 MB
  unsigned short* Q  = (unsigned short*)(ws + 10485760);      // 8 MB
  unsigned short* Kb = (unsigned short*)(ws + 18874368);      // 8 MB
  unsigned short* Vt = (unsigned short*)(ws + 27262976);      // 8 MB
  unsigned short* Ao = (unsigned short*)(ws + 35651584);      // 8 MB  (total 42 MB)

  // single fused fp32->bf16 convert
  cvt_all<<<(N4_X + N4_WQ + N4_WP + 255) / 256, 256, 0, stream>>>(
      x, qkv_w, proj_w, xb, wq, wp);

  // QKV projection: (8192 x 512) @ (1536 x 512)^T, BM=64, 1536 blocks (XCD-mapped)
  gemm_bt<0, 64, 12><<<1536, 256, 0, stream>>>(xb, wq, qkv_b, MTOT, 3 * ED, ED, Q, Kb, Vt, nullptr);

  // flash attention: 512 blocks (XCD-mapped), 8 waves (4 qg x 2 kv-halves)
  attn_kernel<<<512, 512, 0, stream>>>(Q, Kb, Vt, Ao);

  // output projection: (8192 x 512) @ (512 x 512)^T, BM=64, 512 blocks (XCD-mapped)
  gemm_bt<1, 64, 4><<<512, 256, 0, stream>>>(Ao, wp, proj_b, MTOT, ED, ED, nullptr, nullptr, nullptr, out);
}